// Round 7
// baseline (786.485 us; speedup 1.0000x reference)
//
#include <hip/hip_runtime.h>

// SimpleGRU scan: B=2048 seqs, T=2048 steps, H=32, O=2, fp32 backbone.
// Round-13: TWO staggered batch-pairs per wave on the R10b champion (449us,
// 498 cyc/step). Ledger across R8-R12b fits: dot2 issue ~6cyc, DPP ~4cyc ->
// champion busy ~438 (88% issue-bound); residual ~60 idle = serial tail
// trans latency (exp->rcp->fma->cvt->swap ~110cyc, only ~12 independent
// instrs available to fill). MFMA concentrates the elementwise tail (8x
// per-lane -> net loss); split-K TLP duplicates tail/allgather per batch
// (issue-negative, matches pre-R8 finding). The only independent gap-filler
// is ANOTHER pair's recurrence:
//  * 4 batches = 2 independent pairs per wave; per-step program order
//    [ag0, dots0, ag1, dots1, tail0, tail1]. In-order issue overlaps:
//    pair0 last-dot latency under pair1 dot issue; tail0 trans gaps filled
//    by tail1 issue; tail1 tail-end under next step's ag0/dots0 (depend
//    only on h0). Weights SHARED between pairs (48 regs, not 96).
//  * Each pair's code is byte-identical to champion: 6-chain dots (proven
//    vs 9/12-chain regressions R11/R12b), DPP butterfly allgather,
//    pre-scaled weights, single-fma tail.
//  * x staged in LDS as champion, 4 groups; group stride 256B = same-bank
//    2-way broadcast pair (free per m136). unroll 2 (keeps I-cache ~ same
//    as champion's unroll 4 with half the steps/body).
// Predict: ~440-460 cyc per 2 batches -> ~400-425us; VALUBusy 92%+,
// Occupancy ~5.9%, VGPR ~100-120, absmax unchanged.

typedef _Float16 f16x2 __attribute__((ext_vector_type(2)));

__device__ __forceinline__ float fdot2(int a, int b, float c) {
    return __builtin_amdgcn_fdot2(__builtin_bit_cast(f16x2, a),
                                  __builtin_bit_cast(f16x2, b), c, false);
}

__device__ __forceinline__ int pack_pair(float a, float b) {
    f16x2 p;
    p.x = (_Float16)a;
    p.y = (_Float16)b;
    return __builtin_bit_cast(int, p);
}

template<int CTRL>
__device__ __forceinline__ int dppmov(int src) {
    return __builtin_amdgcn_update_dpp(0, src, CTRL, 0xF, 0xF, true);
}

// ---- per-pair step phases (suffix S = 0/1), champion-identical ----
#define ALLGATHER(S)                                                          \
    const unsigned hf##S = (unsigned)__builtin_bit_cast(unsigned short,       \
                                                        (_Float16)h##S);      \
    auto sw##S = __builtin_amdgcn_permlane32_swap(hf##S, hf##S, false, false);\
    const int P0_##S  = ((int)sw##S[1] << 16) | (int)sw##S[0];                \
    const int P1_##S  = dppmov<0xB1 >(P0_##S);                                \
    const int P2_##S  = dppmov<0x4E >(P0_##S);                                \
    const int P3_##S  = dppmov<0x4E >(P1_##S);                                \
    const int P4_##S  = dppmov<0x141>(P0_##S);                                \
    const int P5_##S  = dppmov<0x141>(P1_##S);                                \
    const int P6_##S  = dppmov<0x141>(P2_##S);                                \
    const int P7_##S  = dppmov<0x141>(P3_##S);                                \
    const int P8_##S  = dppmov<0x140>(P0_##S);                                \
    const int P9_##S  = dppmov<0x140>(P1_##S);                                \
    const int P10_##S = dppmov<0x140>(P2_##S);                                \
    const int P11_##S = dppmov<0x140>(P3_##S);                                \
    const int P12_##S = dppmov<0x140>(P4_##S);                                \
    const int P13_##S = dppmov<0x140>(P5_##S);                                \
    const int P14_##S = dppmov<0x140>(P6_##S);                                \
    const int P15_##S = dppmov<0x140>(P7_##S);

#define DOTS(S, XV)                                                           \
    float rA##S = fdot2(P0_##S,  wR[ 0], fmaf((XV), wihr, br));               \
    float zA##S = fdot2(P0_##S,  wZ[ 0], fmaf((XV), wihz, bz));               \
    float nA##S = fdot2(P0_##S,  wN[ 0], bnh);                                \
    float rB##S = fdot2(P8_##S,  wR[ 8], 0.0f);                               \
    float zB##S = fdot2(P8_##S,  wZ[ 8], 0.0f);                               \
    float nB##S = fdot2(P8_##S,  wN[ 8], 0.0f);                               \
    rA##S = fdot2(P1_##S,  wR[ 1], rA##S);                                    \
    zA##S = fdot2(P1_##S,  wZ[ 1], zA##S);                                    \
    nA##S = fdot2(P1_##S,  wN[ 1], nA##S);                                    \
    rB##S = fdot2(P9_##S,  wR[ 9], rB##S);                                    \
    zB##S = fdot2(P9_##S,  wZ[ 9], zB##S);                                    \
    nB##S = fdot2(P9_##S,  wN[ 9], nB##S);                                    \
    rA##S = fdot2(P2_##S,  wR[ 2], rA##S);                                    \
    zA##S = fdot2(P2_##S,  wZ[ 2], zA##S);                                    \
    nA##S = fdot2(P2_##S,  wN[ 2], nA##S);                                    \
    rB##S = fdot2(P10_##S, wR[10], rB##S);                                    \
    zB##S = fdot2(P10_##S, wZ[10], zB##S);                                    \
    nB##S = fdot2(P10_##S, wN[10], nB##S);                                    \
    rA##S = fdot2(P3_##S,  wR[ 3], rA##S);                                    \
    zA##S = fdot2(P3_##S,  wZ[ 3], zA##S);                                    \
    nA##S = fdot2(P3_##S,  wN[ 3], nA##S);                                    \
    rB##S = fdot2(P11_##S, wR[11], rB##S);                                    \
    zB##S = fdot2(P11_##S, wZ[11], zB##S);                                    \
    nB##S = fdot2(P11_##S, wN[11], nB##S);                                    \
    rA##S = fdot2(P4_##S,  wR[ 4], rA##S);                                    \
    zA##S = fdot2(P4_##S,  wZ[ 4], zA##S);                                    \
    nA##S = fdot2(P4_##S,  wN[ 4], nA##S);                                    \
    rB##S = fdot2(P12_##S, wR[12], rB##S);                                    \
    zB##S = fdot2(P12_##S, wZ[12], zB##S);                                    \
    nB##S = fdot2(P12_##S, wN[12], nB##S);                                    \
    rA##S = fdot2(P5_##S,  wR[ 5], rA##S);                                    \
    zA##S = fdot2(P5_##S,  wZ[ 5], zA##S);                                    \
    nA##S = fdot2(P5_##S,  wN[ 5], nA##S);                                    \
    rB##S = fdot2(P13_##S, wR[13], rB##S);                                    \
    zB##S = fdot2(P13_##S, wZ[13], zB##S);                                    \
    nB##S = fdot2(P13_##S, wN[13], nB##S);                                    \
    rA##S = fdot2(P6_##S,  wR[ 6], rA##S);                                    \
    zA##S = fdot2(P6_##S,  wZ[ 6], zA##S);                                    \
    nA##S = fdot2(P6_##S,  wN[ 6], nA##S);                                    \
    rB##S = fdot2(P14_##S, wR[14], rB##S);                                    \
    zB##S = fdot2(P14_##S, wZ[14], zB##S);                                    \
    nB##S = fdot2(P14_##S, wN[14], nB##S);                                    \
    rA##S = fdot2(P7_##S,  wR[ 7], rA##S);                                    \
    zA##S = fdot2(P7_##S,  wZ[ 7], zA##S);                                    \
    nA##S = fdot2(P7_##S,  wN[ 7], nA##S);                                    \
    rB##S = fdot2(P15_##S, wR[15], rB##S);                                    \
    zB##S = fdot2(P15_##S, wZ[15], zB##S);                                    \
    nB##S = fdot2(P15_##S, wN[15], nB##S);

#define TAIL(S, XV)                                                           \
    {                                                                         \
        const float rp = rA##S + rB##S;                                       \
        const float zp = zA##S + zB##S;                                       \
        const float np = nA##S + nB##S;                                       \
        const float er = __builtin_amdgcn_exp2f(rp);                          \
        const float ez = __builtin_amdgcn_exp2f(zp);                          \
        const float r  = __builtin_amdgcn_rcpf(1.0f + er);                    \
        const float z  = __builtin_amdgcn_rcpf(1.0f + ez);                    \
        const float m2omz = fmaf(2.0f, z, -2.0f);                             \
        const float ohz   = fmaf(z, hm1##S, 1.0f);                            \
        const float u  = fmaf(r, np, fmaf((XV), wihn, bni));                  \
        const float et = __builtin_amdgcn_exp2f(u);                           \
        const float ti = __builtin_amdgcn_rcpf(1.0f + et);                    \
        h##S = fmaf(m2omz, ti, ohz);                                          \
    }

__global__ __launch_bounds__(64, 1)
void gru_scan_kernel(const float* __restrict__ x,      // [B,T]
                     const float* __restrict__ w_ih,   // [96,1]
                     const float* __restrict__ w_hh,   // [96,32]
                     const float* __restrict__ b_ih,   // [96]
                     const float* __restrict__ b_hh,   // [96]
                     const float* __restrict__ head_w, // [2,32]
                     const float* __restrict__ head_b, // [2]
                     float* __restrict__ out,          // [B,2]
                     int T)
{
    const int l  = (int)threadIdx.x;
    const int gg = (l >> 4) & 1;                  // batch slot within pair
    const int m  = (l & 15) + ((l >> 5) << 4);    // gate/hidden row 0..31

    __shared__ float hf_s[4][32];                 // fp32 h for head (epilogue)
    __shared__ __align__(16) float x_s[4][2][32]; // [pairgroup][buf][step]

    // ---- orientation probe (wave-uniform; folds into weight packing) ----
    bool lowfirst;
    {
        auto pr = __builtin_amdgcn_permlane32_swap((unsigned)l, (unsigned)l,
                                                   false, false);
        lowfirst = ((int)pr[0] == (l & 31));
    }

    const float NL2E  = -1.44269504088896f;  // -log2(e): sigmoid fold
    const float P2L2E =  2.88539008177793f;  // +2*log2(e): tanh fold

    // butterfly gather order: P[q] holds pair c0 ^ M[q]
    constexpr int M[16] = {0,1,2,3,7,6,5,4,15,14,13,12,8,9,10,11};
    const int c0 = l & 15;

    // ---- shared per-lane weights (both pairs use the same rows) ----
    int wR[16], wZ[16], wN[16];
    {
        const float* pR = w_hh + (     m) * 32;
        const float* pZ = w_hh + (32 + m) * 32;
        const float* pN = w_hh + (64 + m) * 32;
#pragma unroll
        for (int q = 0; q < 16; ++q) {
            const int cc  = c0 ^ M[q];
            const int clo = lowfirst ? cc      : cc + 16;
            const int chi = lowfirst ? cc + 16 : cc;
            wR[q] = pack_pair(NL2E  * pR[clo], NL2E  * pR[chi]);
            wZ[q] = pack_pair(NL2E  * pZ[clo], NL2E  * pZ[chi]);
            wN[q] = pack_pair(P2L2E * pN[clo], P2L2E * pN[chi]);
        }
    }
#pragma unroll
    for (int q = 0; q < 16; ++q) {
        asm volatile("" : "+v"(wR[q]), "+v"(wZ[q]), "+v"(wN[q]));
    }

    // x-path seeds, same pre-scales (all fp32, shared)
    const float wihr = NL2E  * w_ih[m];
    const float wihz = NL2E  * w_ih[32 + m];
    const float wihn = P2L2E * w_ih[64 + m];
    const float br   = NL2E  * (b_ih[m]      + b_hh[m]);
    const float bz   = NL2E  * (b_ih[32 + m] + b_hh[32 + m]);
    const float bni  = P2L2E * b_ih[64 + m];
    const float bnh  = P2L2E * b_hh[64 + m];

    // 4 batches per block: pair0 = rows 4b, 4b+1; pair1 = 4b+2, 4b+3
    const float* xrow0 = x + (size_t)((int)blockIdx.x * 4 + gg    ) * (size_t)T;
    const float* xrow1 = x + (size_t)((int)blockIdx.x * 4 + 2 + gg) * (size_t)T;
    const int    nchunk = T >> 5;   // 32-step chunks (T=2048 -> 64)

    float h0 = 0.0f, h1 = 0.0f;
    x_s[gg    ][0][m] = xrow0[m];
    x_s[2 + gg][0][m] = xrow1[m];
    float xnext0 = (nchunk > 1) ? xrow0[32 + m] : 0.0f;
    float xnext1 = (nchunk > 1) ? xrow1[32 + m] : 0.0f;
    __builtin_amdgcn_wave_barrier();

    for (int c = 0; c < nchunk; ++c) {
        const int buf = c & 1;
        const float* xs0 = &x_s[gg    ][buf][0];
        const float* xs1 = &x_s[2 + gg][buf][0];
#pragma unroll 2
        for (int s = 0; s < 32; ++s) {
            const float xv0  = xs0[s];           // broadcast b32
            const float xv1  = xs1[s];
            const float hm10 = h0 - 1.0f;        // off-path
            const float hm11 = h1 - 1.0f;

            // staggered pairs: [ag0 dots0 | ag1 dots1 | tail0 | tail1]
            ALLGATHER(0)
            DOTS(0, xv0)
            ALLGATHER(1)
            DOTS(1, xv1)
            TAIL(0, xv0)
            TAIL(1, xv1)
        }
        if (c + 1 < nchunk) {
            x_s[gg    ][1 - buf][m] = xnext0;    // stage next chunk
            x_s[2 + gg][1 - buf][m] = xnext1;
            if (c + 2 < nchunk) {
                xnext0 = xrow0[(c + 2) * 32 + m];
                xnext1 = xrow1[(c + 2) * 32 + m];
            }
            __builtin_amdgcn_wave_barrier();
        }
    }

    // ---- head: out[b,o] = head_b[o] + sum_k h[k]*head_w[o,k] ----
    hf_s[gg    ][m] = h0;
    hf_s[2 + gg][m] = h1;
    __builtin_amdgcn_wave_barrier();
    if (l < 8) {
        const int g2 = l >> 1, o = l & 1;
        float acc = head_b[o];
        const float* hw = head_w + o * 32;
#pragma unroll
        for (int k = 0; k < 32; ++k) acc = fmaf(hf_s[g2][k], hw[k], acc);
        out[((int)blockIdx.x * 4 + g2) * 2 + o] = acc;
    }
}

extern "C" void kernel_launch(void* const* d_in, const int* in_sizes, int n_in,
                              void* d_out, int out_size, void* d_ws, size_t ws_size,
                              hipStream_t stream) {
    const float* x      = (const float*)d_in[0];
    const float* w_ih   = (const float*)d_in[1];
    const float* w_hh   = (const float*)d_in[2];
    const float* b_ih   = (const float*)d_in[3];
    const float* b_hh   = (const float*)d_in[4];
    const float* head_w = (const float*)d_in[5];
    const float* head_b = (const float*)d_in[6];
    float* out = (float*)d_out;

    const int B = out_size / 2;          // O = 2
    const int T = in_sizes[0] / B;       // x is [B,T]

    dim3 grid(B / 4), block(64);
    hipLaunchKernelGGL(gru_scan_kernel, grid, block, 0, stream,
                       x, w_ih, w_hh, b_ih, b_hh, head_w, head_b, out, T);
}

// Round 8
// 449.896 us; speedup vs baseline: 1.7481x; 1.7481x over previous
//
#include <hip/hip_runtime.h>

// SimpleGRU scan: B=2048 seqs, T=2048 steps, H=32, O=2, fp32 backbone.
// FINAL (R14 = R10b champion, 449.4us verified): register-only h allgather
// (permlane32_swap + DPP butterfly) + 6-chain interleaved f16-dot2 gate
// matmul + folded single-fma tail.
//
// Why this is terminal (session ledger R8-R13):
//  * Per-step/pair: ~438 cyc VALU issue (dots 48x~6 + allgather ~76 + tail
//    ~74) + ~60 trans-latency idle = 498 cyc (449us @ 1024 waves, 1/SIMD).
//  * The ~60 idle is NOT fillable: R13 (2 staggered pairs/wave) absorbed it
//    per-pair (888 cyc for 4 batches = 444/pair, model-exact) but halves
//    wave count -> wall 758us. TLP shares the same issue port. Split-K
//    duplicates tail+allgather. MFMA (6x 16x16x32_f16, weights as A-frags,
//    bias as C) cuts dot issue 288->~30 but the per-triple trans tail
//    (6 trans x 8cyc) is invariant and 16-batch/wave drops waves to 128:
//    tail-bound wall ~470us+. All alternatives regressed:
//    R9 +61 cyc (gate-sequential), R11 +65 (12-chain JIT-DPP), R12b +55
//    (readlane x, 9-chain), R13 +68%wall (stagger).
//  * Structure locked: 6-chain dots (24cyc dep spacing ~ dot2 latency),
//    x staged in LDS (2-way bank alias = free), DPP butterfly up-front,
//    weights pre-scaled by -log2e (r,z) / +2log2e (n), tail
//    h' = fma(2z-2, ti, 1 + z*(h-1)).

typedef _Float16 f16x2 __attribute__((ext_vector_type(2)));

__device__ __forceinline__ float fdot2(int a, int b, float c) {
    return __builtin_amdgcn_fdot2(__builtin_bit_cast(f16x2, a),
                                  __builtin_bit_cast(f16x2, b), c, false);
}

__device__ __forceinline__ int pack_pair(float a, float b) {
    f16x2 p;
    p.x = (_Float16)a;
    p.y = (_Float16)b;
    return __builtin_bit_cast(int, p);
}

template<int CTRL>
__device__ __forceinline__ int dppmov(int src) {
    return __builtin_amdgcn_update_dpp(0, src, CTRL, 0xF, 0xF, true);
}

__global__ __launch_bounds__(64, 1)
void gru_scan_kernel(const float* __restrict__ x,      // [B,T]
                     const float* __restrict__ w_ih,   // [96,1]
                     const float* __restrict__ w_hh,   // [96,32]
                     const float* __restrict__ b_ih,   // [96]
                     const float* __restrict__ b_hh,   // [96]
                     const float* __restrict__ head_w, // [2,32]
                     const float* __restrict__ head_b, // [2]
                     float* __restrict__ out,          // [B,2]
                     int T)
{
    const int l  = (int)threadIdx.x;
    const int gg = (l >> 4) & 1;                  // batch slot within wave
    const int m  = (l & 15) + ((l >> 5) << 4);    // local gate/hidden row 0..31
    const int b  = (int)blockIdx.x * 2 + gg;

    __shared__ float hf_s[2][32];                 // fp32 h for head
    __shared__ __align__(16) float x_s[2][2][32]; // [group][buf][step]

    // ---- orientation probe: which output of permlane32_swap holds the
    // low-half broadcast? (wave-uniform; folds into weight packing) ----
    bool lowfirst;
    {
        auto pr = __builtin_amdgcn_permlane32_swap((unsigned)l, (unsigned)l,
                                                   false, false);
        lowfirst = ((int)pr[0] == (l & 31));
    }

    const float NL2E  = -1.44269504088896f;  // -log2(e): sigmoid fold
    const float P2L2E =  2.88539008177793f;  // +2*log2(e): tanh fold

    // butterfly gather order: P[q] holds pair c0 ^ M[q]
    constexpr int M[16] = {0,1,2,3,7,6,5,4,15,14,13,12,8,9,10,11};
    const int c0 = l & 15;

    // ---- per-lane weights, packed to match the gather: pair q = columns
    // (cc, cc+16), cc = c0 ^ M[q], low/high per probe. Pre-scaled. ----
    int wR[16], wZ[16], wN[16];
    {
        const float* pR = w_hh + (     m) * 32;
        const float* pZ = w_hh + (32 + m) * 32;
        const float* pN = w_hh + (64 + m) * 32;
#pragma unroll
        for (int q = 0; q < 16; ++q) {
            const int cc  = c0 ^ M[q];
            const int clo = lowfirst ? cc      : cc + 16;
            const int chi = lowfirst ? cc + 16 : cc;
            wR[q] = pack_pair(NL2E  * pR[clo], NL2E  * pR[chi]);
            wZ[q] = pack_pair(NL2E  * pZ[clo], NL2E  * pZ[chi]);
            wN[q] = pack_pair(P2L2E * pN[clo], P2L2E * pN[chi]);
        }
    }
#pragma unroll
    for (int q = 0; q < 16; ++q) {
        asm volatile("" : "+v"(wR[q]), "+v"(wZ[q]), "+v"(wN[q]));
    }

    // x-path seeds, same pre-scales (all fp32)
    const float wihr = NL2E  * w_ih[m];
    const float wihz = NL2E  * w_ih[32 + m];
    const float wihn = P2L2E * w_ih[64 + m];
    const float br   = NL2E  * (b_ih[m]      + b_hh[m]);
    const float bz   = NL2E  * (b_ih[32 + m] + b_hh[32 + m]);
    const float bni  = P2L2E * b_ih[64 + m];
    const float bnh  = P2L2E * b_hh[64 + m];

    const float* xrow   = x + (size_t)b * (size_t)T;
    const int    nchunk = T >> 5;   // 32-step chunks (T=2048 -> 64)

    float h = 0.0f;
    x_s[gg][0][m] = xrow[m];
    float xnext  = (nchunk > 1) ? xrow[32 + m] : 0.0f;
    __builtin_amdgcn_wave_barrier();

    for (int c = 0; c < nchunk; ++c) {
        const int buf = c & 1;
        const float* xs = &x_s[gg][buf][0];
#pragma unroll 4
        for (int s = 0; s < 32; ++s) {
            const float xv  = xs[s];             // broadcast b32
            const float hm1 = h - 1.0f;          // off-path

            // ---- register allgather of h (f16): swap + DPP butterfly ----
            const unsigned hf = (unsigned)__builtin_bit_cast(unsigned short,
                                                             (_Float16)h);
            auto sw = __builtin_amdgcn_permlane32_swap(hf, hf, false, false);
            const int o0 = (int)sw[0];           // low-half bcast (per probe)
            const int o1 = (int)sw[1];           // high-half bcast
            const int P0  = (o1 << 16) | o0;     // pair c0 (hf zero-extended)
            const int P1  = dppmov<0xB1 >(P0);   // c0^1
            const int P2  = dppmov<0x4E >(P0);   // c0^2
            const int P3  = dppmov<0x4E >(P1);   // c0^3
            const int P4  = dppmov<0x141>(P0);   // c0^7
            const int P5  = dppmov<0x141>(P1);   // c0^6
            const int P6  = dppmov<0x141>(P2);   // c0^5
            const int P7  = dppmov<0x141>(P3);   // c0^4
            const int P8  = dppmov<0x140>(P0);   // c0^15
            const int P9  = dppmov<0x140>(P1);   // c0^14
            const int P10 = dppmov<0x140>(P2);   // c0^13
            const int P11 = dppmov<0x140>(P3);   // c0^12
            const int P12 = dppmov<0x140>(P4);   // c0^8
            const int P13 = dppmov<0x140>(P5);   // c0^9
            const int P14 = dppmov<0x140>(P6);   // c0^10
            const int P15 = dppmov<0x140>(P7);   // c0^11

            // ---- 6-chain interleaved dots (24cyc dep spacing) ----
            float rA = fdot2(P0, wR[0], fmaf(xv, wihr, br));
            float zA = fdot2(P0, wZ[0], fmaf(xv, wihz, bz));
            float nA = fdot2(P0, wN[0], bnh);
            float rB = fdot2(P8, wR[8], 0.0f);
            float zB = fdot2(P8, wZ[8], 0.0f);
            float nB = fdot2(P8, wN[8], 0.0f);
            rA = fdot2(P1, wR[1], rA); zA = fdot2(P1, wZ[1], zA); nA = fdot2(P1, wN[1], nA);
            rB = fdot2(P9, wR[9], rB); zB = fdot2(P9, wZ[9], zB); nB = fdot2(P9, wN[9], nB);
            rA = fdot2(P2, wR[2], rA); zA = fdot2(P2, wZ[2], zA); nA = fdot2(P2, wN[2], nA);
            rB = fdot2(P10, wR[10], rB); zB = fdot2(P10, wZ[10], zB); nB = fdot2(P10, wN[10], nB);
            rA = fdot2(P3, wR[3], rA); zA = fdot2(P3, wZ[3], zA); nA = fdot2(P3, wN[3], nA);
            rB = fdot2(P11, wR[11], rB); zB = fdot2(P11, wZ[11], zB); nB = fdot2(P11, wN[11], nB);
            rA = fdot2(P4, wR[4], rA); zA = fdot2(P4, wZ[4], zA); nA = fdot2(P4, wN[4], nA);
            rB = fdot2(P12, wR[12], rB); zB = fdot2(P12, wZ[12], zB); nB = fdot2(P12, wN[12], nB);
            rA = fdot2(P5, wR[5], rA); zA = fdot2(P5, wZ[5], zA); nA = fdot2(P5, wN[5], nA);
            rB = fdot2(P13, wR[13], rB); zB = fdot2(P13, wZ[13], zB); nB = fdot2(P13, wN[13], nB);
            rA = fdot2(P6, wR[6], rA); zA = fdot2(P6, wZ[6], zA); nA = fdot2(P6, wN[6], nA);
            rB = fdot2(P14, wR[14], rB); zB = fdot2(P14, wZ[14], zB); nB = fdot2(P14, wN[14], nB);
            rA = fdot2(P7, wR[7], rA); zA = fdot2(P7, wZ[7], zA); nA = fdot2(P7, wN[7], nA);
            rB = fdot2(P15, wR[15], rB); zB = fdot2(P15, wZ[15], zB); nB = fdot2(P15, wN[15], nB);

            // ---- folded tail ----
            const float rp = rA + rB;
            const float zp = zA + zB;
            const float np = nA + nB;
            const float er = __builtin_amdgcn_exp2f(rp);   // pre-scaled
            const float ez = __builtin_amdgcn_exp2f(zp);
            const float r  = __builtin_amdgcn_rcpf(1.0f + er);
            const float z  = __builtin_amdgcn_rcpf(1.0f + ez);
            const float m2omz = fmaf(2.0f, z, -2.0f);      // 2z-2
            const float ohz   = fmaf(z, hm1, 1.0f);        // 1 - z + z*h
            const float u  = fmaf(r, np, fmaf(xv, wihn, bni));
            const float et = __builtin_amdgcn_exp2f(u);    // e^{2*u_orig}
            const float ti = __builtin_amdgcn_rcpf(1.0f + et);
            h = fmaf(m2omz, ti, ohz);    // (1-z)*tanh + z*h, tanh = 1-2ti
        }
        if (c + 1 < nchunk) {
            x_s[gg][1 - buf][m] = xnext;             // stage next chunk
            if (c + 2 < nchunk) xnext = xrow[(c + 2) * 32 + m];
            __builtin_amdgcn_wave_barrier();
        }
    }

    // ---- head: out[b,o] = head_b[o] + sum_k h[k]*head_w[o,k] (fp32 h) ----
    hf_s[gg][m] = h;
    __builtin_amdgcn_wave_barrier();
    if (l < 4) {
        const int g2 = l >> 1, o = l & 1;
        float acc = head_b[o];
        const float* hw = head_w + o * 32;
#pragma unroll
        for (int k = 0; k < 32; ++k) acc = fmaf(hf_s[g2][k], hw[k], acc);
        out[((int)blockIdx.x * 2 + g2) * 2 + o] = acc;
    }
}

extern "C" void kernel_launch(void* const* d_in, const int* in_sizes, int n_in,
                              void* d_out, int out_size, void* d_ws, size_t ws_size,
                              hipStream_t stream) {
    const float* x      = (const float*)d_in[0];
    const float* w_ih   = (const float*)d_in[1];
    const float* w_hh   = (const float*)d_in[2];
    const float* b_ih   = (const float*)d_in[3];
    const float* b_hh   = (const float*)d_in[4];
    const float* head_w = (const float*)d_in[5];
    const float* head_b = (const float*)d_in[6];
    float* out = (float*)d_out;

    const int B = out_size / 2;          // O = 2
    const int T = in_sizes[0] / B;       // x is [B,T]

    dim3 grid(B / 2), block(64);
    hipLaunchKernelGGL(gru_scan_kernel, grid, block, 0, stream,
                       x, w_ih, w_hh, b_ih, b_hh, head_w, head_b, out, T);
}